// Round 14
// baseline (271.678 us; speedup 1.0000x reference)
//
#include <hip/hip_runtime.h>
#include <hip/hip_bf16.h>
#include <cstdint>

#define B_SZ 2
#define DIM 256
#define L_SEQ 4096
#define D_INNER 512
#define DT_RANK 16
#define D_STATE 16
#define NCHUNK 128
#define CHUNK 32

static constexpr size_t SZ_BIG_SH = (size_t)B_SZ * L_SEQ * D_INNER;  // 4M shorts
static constexpr size_t F_DIR  = (size_t)B_SZ * NCHUNK * D_STATE * D_INNER; // 2M elems/dir (bf16)
static constexpr size_t SD_DIR = (size_t)B_SZ * NCHUNK * D_INNER;           // 128K floats/dir
static constexpr size_t DTR_DIR = (size_t)B_SZ * L_SEQ * DT_RANK;           // 128K shorts/dir

typedef __attribute__((ext_vector_type(8))) short short8v;
typedef __attribute__((ext_vector_type(4))) short short4v;
typedef __attribute__((ext_vector_type(4))) float f32x4;

__device__ __forceinline__ float silu_f(float v) {
    return v / (1.0f + __expf(-v));
}
__device__ __forceinline__ float softplus_fast(float v) {
    return (v > 15.0f) ? v : __logf(1.0f + __expf(v));
}
__device__ __forceinline__ short f2bf(float f) {   // RNE fp32 -> bf16 bits
    uint32_t u = __float_as_uint(f);
    u += 0x7fffu + ((u >> 16) & 1u);
    return (short)(u >> 16);
}
__device__ __forceinline__ float bf2f(short s) {
    return __uint_as_float(((uint32_t)(uint16_t)s) << 16);
}
// direction map: sequence position p -> original flat index l (involutions)
__device__ __forceinline__ int dir_map(int p, int dm) {
    if (dm == 0) return p;
    if (dm == 1) return (L_SEQ - 1) - p;
    return ((p & 63) << 6) | (p >> 6);   // 64x64 transpose
}
// dA[s] = r1^(s+1) via binary power tree (A_log = log(1..16) structure)
__device__ __forceinline__ void pow_dA(float r1, float* dA) {
    const float r2 = r1 * r1, r4 = r2 * r2, r8 = r4 * r4;
    dA[0] = r1;         dA[1] = r2;         dA[2] = r2 * r1;    dA[3] = r4;
    dA[4] = r4 * r1;    dA[5] = r4 * r2;    dA[6] = r4 * dA[2]; dA[7] = r8;
    dA[8] = r8 * r1;    dA[9] = r8 * r2;    dA[10] = r8 * dA[2]; dA[11] = r8 * r4;
    dA[12] = r8 * dA[4]; dA[13] = r8 * dA[5]; dA[14] = r8 * dA[6]; dA[15] = r8 * r8;
}

// ---------------------------------------------------------------------------
// Kernel 0: convert weights to bf16.
// ---------------------------------------------------------------------------
__global__ __launch_bounds__(256) void k_cvt(
    const float* __restrict__ Wi, const float* __restrict__ Wo,
    const float* __restrict__ xp0, const float* __restrict__ xp1, const float* __restrict__ xp2,
    const float* __restrict__ dw0, const float* __restrict__ dw1, const float* __restrict__ dw2,
    short* __restrict__ Wib, short* __restrict__ Wob,
    short* __restrict__ xpwb, short* __restrict__ dtwb)
{
    const int idx = blockIdx.x * 256 + threadIdx.x;   // float4 chunk id
    const float* src; short* dst; int off;
    if (idx < 65536)        { src = Wi; dst = Wib; off = idx; }
    else if (idx < 98304)   { src = Wo; dst = Wob; off = idx - 65536; }
    else if (idx < 116736)  {
        int k = idx - 98304; const int d = k / 6144; k -= d * 6144;
        src = d == 0 ? xp0 : (d == 1 ? xp1 : xp2);
        dst = xpwb + (size_t)d * 24576; off = k;
    } else {
        int k = idx - 116736; const int d = k / 2048; k -= d * 2048;
        src = d == 0 ? dw0 : (d == 1 ? dw1 : dw2);
        dst = dtwb + (size_t)d * 8192; off = k;
    }
    const float4 v = *(const float4*)(src + (size_t)off * 4);
    short4v p = {f2bf(v.x), f2bf(v.y), f2bf(v.z), f2bf(v.w)};
    *(short4v*)(dst + (size_t)off * 4) = p;
}

// ---------------------------------------------------------------------------
// Kernel 1a: LayerNorm via LDS transpose tile; writes xn as bf16.
// ---------------------------------------------------------------------------
__global__ __launch_bounds__(256) void k_ln_t(
    const float* __restrict__ x, const float* __restrict__ lnw,
    const float* __restrict__ lnb, short* __restrict__ xnb)
{
    __shared__ float xt[64][257];
    __shared__ float red[2][4][64];
    __shared__ float muS[64], rsS[64];
    __shared__ float lnwS[DIM], lnbS[DIM];

    const int b  = blockIdx.x >> 6;
    const int l0 = (blockIdx.x & 63) << 6;
    const int t  = threadIdx.x;
    lnwS[t] = lnw[t]; lnbS[t] = lnb[t];

    const float* xb = x + (size_t)b * DIM * L_SEQ + l0;
#pragma unroll
    for (int it = 0; it < 16; ++it) {
        const int idx = it * 256 + t;
        const int c = idx >> 4, pos = (idx & 15) << 2;
        const float4 v = *(const float4*)(xb + (size_t)c * L_SEQ + pos);
        xt[pos + 0][c] = v.x; xt[pos + 1][c] = v.y;
        xt[pos + 2][c] = v.z; xt[pos + 3][c] = v.w;
    }
    __syncthreads();
    {
        const int l = t & 63, cq = t >> 6;
        float sum = 0.f, sq = 0.f;
        for (int c = cq * 64; c < cq * 64 + 64; ++c) {
            const float v = xt[l][c];
            sum += v; sq += v * v;
        }
        red[0][cq][l] = sum; red[1][cq][l] = sq;
    }
    __syncthreads();
    if (t < 64) {
        const float s  = red[0][0][t] + red[0][1][t] + red[0][2][t] + red[0][3][t];
        const float q2 = red[1][0][t] + red[1][1][t] + red[1][2][t] + red[1][3][t];
        const float mu  = s * (1.0f / DIM);
        const float var = q2 * (1.0f / DIM) - mu * mu;
        muS[t] = mu; rsS[t] = rsqrtf(var + 1e-5f);
    }
    __syncthreads();
#pragma unroll
    for (int it = 0; it < 32; ++it) {
        const int idx = it * 256 + t;
        const int l = idx >> 7, cp = (idx & 127) << 1;
        const float mu = muS[l], rs = rsS[l];
        short2 p;
        p.x = f2bf((xt[l][cp + 0] - mu) * rs * lnwS[cp + 0] + lnbS[cp + 0]);
        p.y = f2bf((xt[l][cp + 1] - mu) * rs * lnwS[cp + 1] + lnbS[cp + 1]);
        *(short2*)(xnb + (size_t)((b * L_SEQ) + l0 + l) * DIM + cp) = p;
    }
}

// ---------------------------------------------------------------------------
// Kernel 1b: in_proj via MFMA; outputs xin and sz as bf16.
// ---------------------------------------------------------------------------
__global__ __launch_bounds__(256) void k_inproj_mfma(
    const short* __restrict__ xnb, const short* __restrict__ Wib,
    short* __restrict__ xinb, short* __restrict__ szb)
{
    const int mblk = blockIdx.x >> 2;
    const int q    = blockIdx.x & 3;
    const int t = threadIdx.x;
    const int w = t >> 6, l = t & 63;
    const int m0 = mblk * 64 + w * 16;
    const int n0 = q * 256;
    const int lrow = l & 15, lk = l >> 4;

    short8v a[8];
    {
        const short* ap = xnb + (size_t)(m0 + lrow) * DIM + lk * 8;
#pragma unroll
        for (int kk = 0; kk < 8; ++kk)
            a[kk] = *(const short8v*)(ap + kk * 32);
    }

#pragma unroll 4
    for (int nf = 0; nf < 16; ++nf) {
        const int n = n0 + nf * 16 + lrow;
        const short* bp = Wib + (size_t)n * DIM + lk * 8;
        f32x4 acc = {0.f, 0.f, 0.f, 0.f};
#pragma unroll
        for (int kk = 0; kk < 8; ++kk)
            acc = __builtin_amdgcn_mfma_f32_16x16x32_bf16(
                a[kk], *(const short8v*)(bp + kk * 32), acc, 0, 0, 0);
        const int col = n;
        const int r0  = m0 + lk * 4;
        if (n0 < D_INNER) {
#pragma unroll
            for (int j = 0; j < 4; ++j)
                xinb[(size_t)(r0 + j) * D_INNER + col] = f2bf(acc[j]);
        } else {
#pragma unroll
            for (int j = 0; j < 4; ++j)
                szb[(size_t)(r0 + j) * D_INNER + (col - D_INNER)] = f2bf(silu_f(acc[j]));
        }
    }
}

// ---------------------------------------------------------------------------
// Kernel 2: causal conv (K=4) + SiLU; bf16 in/out, sliding-window regs.
// ---------------------------------------------------------------------------
__global__ __launch_bounds__(256) void k_conv3(
    const short* __restrict__ xinb,
    const float* __restrict__ cw0, const float* __restrict__ cw1, const float* __restrict__ cw2,
    const float* __restrict__ cb0, const float* __restrict__ cb1, const float* __restrict__ cb2,
    short* __restrict__ xcbb, int dir_base, size_t xcb_str)
{
    const int rel = blockIdx.x >> 9;
    const int rem = blockIdx.x & 511;
    const int dir = dir_base + rel;
    const int b   = rem >> 8;
    const int p0  = (rem & 255) << 4;
    const int t   = threadIdx.x;

    const float* cw = dir == 0 ? cw0 : (dir == 1 ? cw1 : cw2);
    const float* cb = dir == 0 ? cb0 : (dir == 1 ? cb1 : cb2);
    short* xcb = xcbb + (size_t)rel * xcb_str;

    __shared__ short s[19][D_INNER];   // 19.5 KB
    for (int i = 0; i < 19; ++i) {
        const int pk = p0 - 3 + i;
        short2 v = {0, 0};
        if (pk >= 0) {
            const int lo = dir_map(pk, dir);
            v = *(const short2*)(xinb + ((size_t)b * L_SEQ + lo) * D_INNER + t * 2);
        }
        *(short2*)&s[i][t * 2] = v;
    }
    __syncthreads();

#pragma unroll
    for (int half = 0; half < 2; ++half) {
        const int d = half * 256 + t;
        const float4 wv = *(const float4*)(cw + d * 4);
        const float bb = cb[d];
        float x0 = bf2f(s[0][d]), x1 = bf2f(s[1][d]), x2 = bf2f(s[2][d]);
#pragma unroll
        for (int i = 0; i < 16; ++i) {
            const float x3 = bf2f(s[i + 3][d]);
            const float a = bb + wv.x * x0 + wv.y * x1 + wv.z * x2 + wv.w * x3;
            xcb[((size_t)b * L_SEQ + p0 + i) * D_INNER + d] = f2bf(silu_f(a));
            x0 = x1; x1 = x2; x2 = x3;
        }
    }
}

// ---------------------------------------------------------------------------
// Kernel 3: x_proj via MFMA, K-split across 4 waves. Writes dtr (bf16,
// [row][16]) and bc; dt_proj is DEFERRED to the scan kernels (rank-16).
// ---------------------------------------------------------------------------
__global__ __launch_bounds__(256) void k_proj3_mfma(
    const short* __restrict__ xcbb, const short* __restrict__ xpwb,
    short* __restrict__ dtrb, float* __restrict__ bcbuf,
    int dir_base, size_t xcb_str, size_t bc_str)
{
    const int rel = blockIdx.x >> 9;         // 512 blocks per dir
    const int rem = blockIdx.x & 511;
    const int dir = dir_base + rel;
    const int m0  = rem * 16;
    const int t = threadIdx.x;
    const int w = t >> 6, l = t & 63;        // w = K-quarter
    const int lrow = l & 15, lk = l >> 4;

    const short* xcb = xcbb + (size_t)rel * xcb_str;
    const short* xpw = xpwb + (size_t)dir * (48 * 512);
    short* dtr = dtrb + (size_t)dir * DTR_DIR;
    float* bc = bcbuf + (size_t)rel * bc_str;

    __shared__ float red[4][3][16][17];   // padded row stride 17: no conflicts

    short8v a[4];
    {
        const short* ap = xcb + (size_t)(m0 + lrow) * D_INNER + w * 128 + lk * 8;
#pragma unroll
        for (int kk = 0; kk < 4; ++kk)
            a[kk] = *(const short8v*)(ap + kk * 32);
    }

#pragma unroll
    for (int nf = 0; nf < 3; ++nf) {
        f32x4 acc = {0.f, 0.f, 0.f, 0.f};
        const short* bp = xpw + (size_t)(nf * 16 + lrow) * D_INNER + w * 128 + lk * 8;
#pragma unroll
        for (int kk = 0; kk < 4; ++kk)
            acc = __builtin_amdgcn_mfma_f32_16x16x32_bf16(
                a[kk], *(const short8v*)(bp + kk * 32), acc, 0, 0, 0);
#pragma unroll
        for (int j = 0; j < 4; ++j)
            red[w][nf][lk * 4 + j][lrow] = acc[j];
    }
    __syncthreads();

#pragma unroll
    for (int i = 0; i < 3; ++i) {
        const int nf = i;
        const int row = (t >> 4) & 15, col = t & 15;
        const float v = red[0][nf][row][col] + red[1][nf][row][col]
                      + red[2][nf][row][col] + red[3][nf][row][col];
        if (nf == 0) dtr[(size_t)(m0 + row) * DT_RANK + col] = f2bf(v);
        else         bc[(size_t)(m0 + row) * 32 + (nf - 1) * 16 + col] = v;
    }
}

// block-uniform fast-structure vote: A_log row ~ log(1..16)?
__device__ __forceinline__ bool fast_vote(const float* Al_d, int t, int* flagS) {
    bool ok = true;
    const float a0 = __expf(Al_d[0]);   // ~1
#pragma unroll
    for (int s = 1; s < 16; ++s) {
        const float v = __expf(Al_d[s]);
        const float e = (float)(s + 1) * a0;
        ok = ok && (fabsf(v - e) <= 1e-3f * e);
    }
    if (t == 0) *flagS = 1;
    __syncthreads();
    if (!ok) *flagS = 0;
    __syncthreads();
    return *flagS != 0;
}

// ---------------------------------------------------------------------------
// Scan bodies. dt recomputed per step from dtr (LDS broadcast) and dtw row
// held in VGPRs: dt = softplus(dot16(dtr, w) + bias). F/Hin stored bf16.
// ---------------------------------------------------------------------------
template<bool FAST>
__device__ __forceinline__ void scan1_body(
    const short* dtrp,                // dtr + rowbase*16 (full row)
    const short* xcp, const float* bcp,
    short (*dtrS)[16], short (*xcs)[256], float (*bcs)[16],
    const float* Al_d, const short* dtw_d, float bias,
    int t, short* F_o, float* SD_o)
{
    float wdt[16];
#pragma unroll
    for (int k = 0; k < 16; ++k) wdt[k] = bf2f(dtw_d[k]);

    float As20, As2[16];
    if (FAST) {
        As20 = -__expf(Al_d[0]) * 1.44269504f;
    } else {
#pragma unroll
        for (int s = 0; s < 16; ++s) As2[s] = -__expf(Al_d[s]) * 1.44269504f;
        As20 = As2[0];
    }
    float h[16];
#pragma unroll
    for (int s = 0; s < 16; ++s) h[s] = 0.f;
    float sumdt = 0.f;

    for (int tile = 0; tile < CHUNK / 16; ++tile) {
        const int p0 = tile * 16;
        dtrS[t >> 4][t & 15] = dtrp[(size_t)(p0 + (t >> 4)) * DT_RANK + (t & 15)];
#pragma unroll
        for (int rep = 0; rep < 2; ++rep) {
            const int idx = rep * 256 + t;
            const int jr = idx >> 5, c8 = (idx & 31) << 3;
            *(short8v*)&xcs[jr][c8] = *(const short8v*)(xcp + (size_t)(p0 + jr) * D_INNER + c8);
        }
        if (t < 64) {
            const int jr = t >> 2, c4 = (t & 3) << 2;
            *(float4*)&bcs[jr][c4] = *(const float4*)(bcp + (size_t)(p0 + jr) * 32 + c4);
        }
        __syncthreads();

#pragma unroll
        for (int j = 0; j < 16; ++j) {
            float a = bias;
#pragma unroll
            for (int k = 0; k < 16; ++k)
                a = fmaf(bf2f(dtrS[j][k]), wdt[k], a);
            const float dtv = softplus_fast(a);
            const float xv  = bf2f(xcs[j][t]);
            sumdt += dtv;
            const float dtx = dtv * xv;
            float Bv[16];
#pragma unroll
            for (int s4 = 0; s4 < 4; ++s4) {
                const float4 bb = *(const float4*)&bcs[j][s4 * 4];
                Bv[s4 * 4 + 0] = bb.x; Bv[s4 * 4 + 1] = bb.y;
                Bv[s4 * 4 + 2] = bb.z; Bv[s4 * 4 + 3] = bb.w;
            }
            if (FAST) {
                float dA[16];
                pow_dA(exp2f(dtv * As20), dA);
#pragma unroll
                for (int s = 0; s < 16; ++s)
                    h[s] = fmaf(dA[s], h[s], dtx * Bv[s]);
            } else {
#pragma unroll
                for (int s = 0; s < 16; ++s)
                    h[s] = fmaf(exp2f(dtv * As2[s]), h[s], dtx * Bv[s]);
            }
        }
        __syncthreads();
    }
#pragma unroll
    for (int s = 0; s < 16; ++s)
        F_o[(size_t)s * D_INNER] = f2bf(h[s]);
    *SD_o = sumdt;
}

template<bool FAST>
__device__ __forceinline__ void scan2_body(
    const short* dtrp, const short* xcp, const float* bcp,
    short* yp,
    short (*dtrS)[16], short (*xcs)[256], float (*bcs)[32],
    const float* Al_d, const short* dtw_d, float bias,
    int t, float Dv, const short* Hin_o)
{
    float wdt[16];
#pragma unroll
    for (int k = 0; k < 16; ++k) wdt[k] = bf2f(dtw_d[k]);

    float As20, As2[16];
    if (FAST) {
        As20 = -__expf(Al_d[0]) * 1.44269504f;
    } else {
#pragma unroll
        for (int s = 0; s < 16; ++s) As2[s] = -__expf(Al_d[s]) * 1.44269504f;
        As20 = As2[0];
    }
    float h[16];
#pragma unroll
    for (int s = 0; s < 16; ++s)
        h[s] = bf2f(Hin_o[(size_t)s * D_INNER]);

    for (int tile = 0; tile < CHUNK / 16; ++tile) {
        const int p0 = tile * 16;
        dtrS[t >> 4][t & 15] = dtrp[(size_t)(p0 + (t >> 4)) * DT_RANK + (t & 15)];
#pragma unroll
        for (int rep = 0; rep < 2; ++rep) {
            const int idx = rep * 256 + t;
            const int jr = idx >> 5, c8 = (idx & 31) << 3;
            *(short8v*)&xcs[jr][c8] = *(const short8v*)(xcp + (size_t)(p0 + jr) * D_INNER + c8);
        }
        if (t < 128) {
            const int jr = t >> 3, c4 = (t & 7) << 2;
            *(float4*)&bcs[jr][c4] = *(const float4*)(bcp + (size_t)(p0 + jr) * 32 + c4);
        }
        __syncthreads();

#pragma unroll
        for (int j = 0; j < 16; ++j) {
            float a = bias;
#pragma unroll
            for (int k = 0; k < 16; ++k)
                a = fmaf(bf2f(dtrS[j][k]), wdt[k], a);
            const float dtv = softplus_fast(a);
            const float xv  = bf2f(xcs[j][t]);
            const float dtx = dtv * xv;
            float Bv[16], Cv[16];
#pragma unroll
            for (int s4 = 0; s4 < 4; ++s4) {
                const float4 bb = *(const float4*)&bcs[j][s4 * 4];
                const float4 cc = *(const float4*)&bcs[j][16 + s4 * 4];
                Bv[s4 * 4 + 0] = bb.x; Bv[s4 * 4 + 1] = bb.y;
                Bv[s4 * 4 + 2] = bb.z; Bv[s4 * 4 + 3] = bb.w;
                Cv[s4 * 4 + 0] = cc.x; Cv[s4 * 4 + 1] = cc.y;
                Cv[s4 * 4 + 2] = cc.z; Cv[s4 * 4 + 3] = cc.w;
            }
            float y = xv * Dv;
            if (FAST) {
                float dA[16];
                pow_dA(exp2f(dtv * As20), dA);
#pragma unroll
                for (int s = 0; s < 16; ++s) {
                    h[s] = fmaf(dA[s], h[s], dtx * Bv[s]);
                    y = fmaf(h[s], Cv[s], y);
                }
            } else {
#pragma unroll
                for (int s = 0; s < 16; ++s) {
                    h[s] = fmaf(exp2f(dtv * As2[s]), h[s], dtx * Bv[s]);
                    y = fmaf(h[s], Cv[s], y);
                }
            }
            yp[(size_t)(p0 + j) * D_INNER + t] = f2bf(y);
        }
        __syncthreads();
    }
}

// ---------------------------------------------------------------------------
// Kernel 4a: per-chunk transition. Grid per dir = 2(b) x 128(chunk) x 2(half).
// ---------------------------------------------------------------------------
__global__ __launch_bounds__(256, 4) void k_scan1(
    const short* __restrict__ dtrb, const short* __restrict__ xcbb,
    const float* __restrict__ bcb, const short* __restrict__ dtwb,
    const float* __restrict__ dtb0, const float* __restrict__ dtb1, const float* __restrict__ dtb2,
    const float* __restrict__ Al0, const float* __restrict__ Al1, const float* __restrict__ Al2,
    short* __restrict__ Fg, float* __restrict__ SDg,
    int dir_base, size_t xcb_str, size_t bc_str)
{
    const int rel = blockIdx.x >> 9;         // 512 blocks per dir
    const int rem = blockIdx.x & 511;
    const int dir = dir_base + rel;
    const int b     = rem >> 8;
    const int chunk = (rem >> 1) & 127;
    const int half  = rem & 1;
    const int t = threadIdx.x;
    const int d = half * 256 + t;

    const short* dtrg = dtrb + (size_t)dir * DTR_DIR;
    const short* xcg  = xcbb + (size_t)rel * xcb_str;
    const float* bcg  = bcb + (size_t)rel * bc_str;
    const short* dtw  = dtwb + (size_t)dir * (512 * 16);
    const float* dtb  = dir == 0 ? dtb0 : (dir == 1 ? dtb1 : dtb2);
    const float* Al   = dir == 0 ? Al0 : (dir == 1 ? Al1 : Al2);
    short* F  = Fg  + (size_t)rel * F_DIR;
    float* SD = SDg + (size_t)rel * SD_DIR;

    __shared__ short dtrS[16][16];   // 0.5 KB
    __shared__ short xcs[16][256];   // 8 KB
    __shared__ float bcs[16][16];    // 1 KB
    __shared__ int flagS;

    const size_t rowbase = (size_t)b * L_SEQ + chunk * CHUNK;
    const short* dtrp = dtrg + rowbase * DT_RANK;
    const short* xcp  = xcg + rowbase * D_INNER + half * 256;
    const float* bcp  = bcg + rowbase * 32;
    const float* Al_d = Al + d * D_STATE;
    const size_t fo  = ((size_t)b * NCHUNK + chunk) * (D_STATE * D_INNER) + d;
    const size_t sdo = ((size_t)b * NCHUNK + chunk) * D_INNER + d;

    const bool fast = fast_vote(Al_d, t, &flagS);
    if (fast) scan1_body<true >(dtrp, xcp, bcp, dtrS, xcs, bcs, Al_d,
                                dtw + d * 16, dtb[d], t, F + fo, SD + sdo);
    else      scan1_body<false>(dtrp, xcp, bcp, dtrS, xcs, bcs, Al_d,
                                dtw + d * 16, dtb[d], t, F + fo, SD + sdo);
}

// ---------------------------------------------------------------------------
// Kernel 4b: sequential combine; Hin (bf16) written IN PLACE over F.
// P recomputed from sumdt: P = exp2(As2 * sumdt) (valid for any A).
// ---------------------------------------------------------------------------
__global__ __launch_bounds__(256) void k_comb(
    short* __restrict__ Fg, const float* __restrict__ SDg,
    const float* __restrict__ Al0, const float* __restrict__ Al1, const float* __restrict__ Al2,
    int dir_base)
{
    const int rel = blockIdx.x >> 6;         // 64 blocks per dir
    const int dir = dir_base + rel;
    const int gid = (blockIdx.x & 63) * 256 + threadIdx.x;   // 16384
    const int b   = gid >> 13;
    const int rem = gid & 8191;              // s*512 + d
    const int s   = rem >> 9;
    const int d   = rem & 511;

    const float* Al = dir == 0 ? Al0 : (dir == 1 ? Al1 : Al2);
    const float As2 = -__expf(Al[d * D_STATE + s]) * 1.44269504f;

    short* F        = Fg  + (size_t)rel * F_DIR;
    const float* SD = SDg + (size_t)rel * SD_DIR;

    float h = 0.f;
    for (int c = 0; c < NCHUNK; ++c) {
        const size_t base = (size_t)(b * NCHUNK + c);
        const size_t i  = (base << 13) + rem;
        const float sd  = SD[(base << 9) + d];
        const float P   = exp2f(As2 * sd);
        const float fv  = bf2f(F[i]);
        F[i] = f2bf(h);                      // Hin for chunk c
        h = fmaf(P, h, fv);
    }
}

// ---------------------------------------------------------------------------
// Kernel 4c: full scan; y bf16 to yb. Hin read from F (in-place, bf16).
// ---------------------------------------------------------------------------
__global__ __launch_bounds__(256, 4) void k_scan2(
    const short* __restrict__ dtrb, const short* __restrict__ xcbb,
    const float* __restrict__ bcb, const short* __restrict__ dtwb,
    const float* __restrict__ dtb0, const float* __restrict__ dtb1, const float* __restrict__ dtb2,
    const float* __restrict__ Al0, const float* __restrict__ Al1, const float* __restrict__ Al2,
    const float* __restrict__ Dp0, const float* __restrict__ Dp1, const float* __restrict__ Dp2,
    const short* __restrict__ Hing, short* __restrict__ ybg,
    int dir_base, size_t xcb_str, size_t bc_str)
{
    const int rel = blockIdx.x >> 9;
    const int rem = blockIdx.x & 511;
    const int dir = dir_base + rel;
    const int b     = rem >> 8;
    const int chunk = (rem >> 1) & 127;
    const int half  = rem & 1;
    const int t = threadIdx.x;
    const int d = half * 256 + t;

    const short* dtrg = dtrb + (size_t)dir * DTR_DIR;
    const short* xcg  = xcbb + (size_t)rel * xcb_str;
    const float* bcg  = bcb + (size_t)rel * bc_str;
    const short* dtw  = dtwb + (size_t)dir * (512 * 16);
    const float* dtb  = dir == 0 ? dtb0 : (dir == 1 ? dtb1 : dtb2);
    const float* Al   = dir == 0 ? Al0 : (dir == 1 ? Al1 : Al2);
    const float* Dpp  = dir == 0 ? Dp0 : (dir == 1 ? Dp1 : Dp2);
    const short* Hin  = Hing + (size_t)rel * F_DIR;
    short* yg         = ybg + (size_t)dir * SZ_BIG_SH;

    __shared__ short dtrS[16][16];
    __shared__ short xcs[16][256];
    __shared__ float bcs[16][32];
    __shared__ int flagS;

    const size_t rowbase = (size_t)b * L_SEQ + chunk * CHUNK;
    const short* dtrp = dtrg + rowbase * DT_RANK;
    const short* xcp  = xcg + rowbase * D_INNER + half * 256;
    short* yp         = yg + rowbase * D_INNER + half * 256;
    const float* bcp  = bcg + rowbase * 32;
    const float* Al_d = Al + d * D_STATE;
    const float Dv = Dpp[d];
    const size_t fo = ((size_t)b * NCHUNK + chunk) * (D_STATE * D_INNER) + d;

    const bool fast = fast_vote(Al_d, t, &flagS);
    if (fast) scan2_body<true >(dtrp, xcp, bcp, yp, dtrS, xcs, bcs, Al_d,
                                dtw + d * 16, dtb[d], t, Dv, Hin + fo);
    else      scan2_body<false>(dtrp, xcp, bcp, yp, dtrS, xcs, bcs, Al_d,
                                dtw + d * 16, dtb[d], t, Dv, Hin + fo);
}

// ---------------------------------------------------------------------------
// Kernel 5: out_proj via MFMA; y0/y1/y2/sz all bf16.
// ---------------------------------------------------------------------------
__global__ __launch_bounds__(256) void k_out3_mfma(
    const short* __restrict__ yall, const short* __restrict__ szb,
    const short* __restrict__ Wob, const float* __restrict__ x,
    float* __restrict__ out)
{
    __shared__ short ytb[32][512];           // 32 KB
    const int tile = blockIdx.x;
    const int b  = tile >> 7;
    const int l0 = (tile & 127) << 5;
    const int t  = threadIdx.x;

    const short* y0 = yall;
    const short* y1 = yall + SZ_BIG_SH;
    const short* y2 = yall + 2 * SZ_BIG_SH;
    const size_t rb = (size_t)b * L_SEQ;

#pragma unroll
    for (int it = 0; it < 8; ++it) {
        const int idx = it * 256 + t;        // 2048 chunks of 8
        const int r  = idx >> 6;
        const int c8 = idx & 63;
        const int lrow = l0 + r;
        const int p1 = (L_SEQ - 1) - lrow;
        const int p2 = ((lrow & 63) << 6) | (lrow >> 6);
        const short8v s0 = *(const short8v*)(y0 + (rb + lrow) * D_INNER + c8 * 8);
        const short8v s1 = *(const short8v*)(y1 + (rb + p1)   * D_INNER + c8 * 8);
        const short8v s2 = *(const short8v*)(y2 + (rb + p2)   * D_INNER + c8 * 8);
        const short8v sv = *(const short8v*)(szb + (rb + lrow) * D_INNER + c8 * 8);
        short8v pk;
#pragma unroll
        for (int i = 0; i < 8; ++i)
            pk[i] = f2bf((bf2f(s0[i]) + bf2f(s1[i]) + bf2f(s2[i])) * bf2f(sv[i]));
        *(short8v*)&ytb[r][(c8 ^ (r & 7)) * 8] = pk;
    }
    __syncthreads();

    const int w = t >> 6, l = t & 63;
    const int lrow = l & 15, lk = l >> 4;
    const int nf = w & 1;
    const int j0 = (w >> 1) * 128;
    const int brow = nf * 16 + lrow;

    f32x4 acc[8];
#pragma unroll
    for (int jf = 0; jf < 8; ++jf) acc[jf] = {0.f, 0.f, 0.f, 0.f};

#pragma unroll 4
    for (int kk = 0; kk < 16; ++kk) {
        const int c8 = kk * 4 + lk;
        const short8v bfrag = *(const short8v*)&ytb[brow][(c8 ^ (brow & 7)) * 8];
#pragma unroll
        for (int jf = 0; jf < 8; ++jf) {
            const short8v afrag = *(const short8v*)(
                Wob + (size_t)(j0 + jf * 16 + lrow) * D_INNER + kk * 32 + lk * 8);
            acc[jf] = __builtin_amdgcn_mfma_f32_16x16x32_bf16(afrag, bfrag, acc[jf], 0, 0, 0);
        }
    }

    const int lcol = l0 + nf * 16 + lrow;
#pragma unroll
    for (int jf = 0; jf < 8; ++jf) {
        const int jr0 = j0 + jf * 16 + lk * 4;
#pragma unroll
        for (int j = 0; j < 4; ++j) {
            const size_t o = ((size_t)b * DIM + jr0 + j) * L_SEQ + lcol;
            out[o] = x[o] + acc[jf][j];
        }
    }
}

// ---------------------------------------------------------------------------
extern "C" void kernel_launch(void* const* d_in, const int* in_sizes, int n_in,
                              void* d_out, int out_size, void* d_ws, size_t ws_size,
                              hipStream_t stream)
{
    const float* x       = (const float*)d_in[0];
    const float* ln_w    = (const float*)d_in[1];
    const float* ln_b    = (const float*)d_in[2];
    const float* in_proj = (const float*)d_in[3];
    const float* conv_w[3] = {(const float*)d_in[4],  (const float*)d_in[10], (const float*)d_in[16]};
    const float* conv_b[3] = {(const float*)d_in[5],  (const float*)d_in[11], (const float*)d_in[17]};
    const float* xpw[3]    = {(const float*)d_in[6],  (const float*)d_in[12], (const float*)d_in[18]};
    const float* dtw[3]    = {(const float*)d_in[7],  (const float*)d_in[13], (const float*)d_in[19]};
    const float* dtb[3]    = {(const float*)d_in[8],  (const float*)d_in[14], (const float*)d_in[20]};
    const float* Dp[3]     = {(const float*)d_in[9],  (const float*)d_in[15], (const float*)d_in[21]};
    const float* A_log[3]  = {(const float*)d_in[22], (const float*)d_in[23], (const float*)d_in[24]};
    const float* out_proj  = (const float*)d_in[25];
    float* out = (float*)d_out;
    (void)in_sizes; (void)n_in; (void)out_size;

    const size_t NROW   = (size_t)B_SZ * L_SEQ;                       // 8192
    // float-slot sizes
    const size_t SZ_XNB = NROW * DIM / 2;            // 1,048,576
    const size_t SZ_WIB = 262144 / 2;
    const size_t SZ_WOB = 131072 / 2;
    const size_t SZ_XPW = 3 * 24576 / 2;
    const size_t SZ_DTW = 3 * 8192 / 2;
    const size_t SZ_BH  = NROW * D_INNER / 2;        // bf16 big buf = 2,097,152
    const size_t SZ_BC  = NROW * 32;                 // 262,144
    const size_t SZ_F   = F_DIR / 2;                 // bf16 F per dir (float slots)
    const size_t SZ_DTR = DTR_DIR / 2;               // bf16 dtr per dir

    const size_t need_merged =
        SZ_XNB + SZ_WIB + SZ_WOB + SZ_XPW + SZ_DTW +
        2 * SZ_BH + 3 * SZ_BH + 3 * SZ_DTR + 3 * SZ_BH + 3 * SZ_BC +
        3 * (SZ_F + SD_DIR);
    const bool merged = ws_size >= need_merged * sizeof(float);
    const int ndir = merged ? 3 : 1;
    const size_t xcb_str = merged ? (SZ_BH * 2) : 0;   // SHORT units
    const size_t bc_str  = merged ? SZ_BC : 0;

    float* ws   = (float*)d_ws;
    float* p    = ws;
    short* xnb  = (short*)p;  p += SZ_XNB;
    short* Wib  = (short*)p;  p += SZ_WIB;
    short* Wob  = (short*)p;  p += SZ_WOB;
    short* xpwb = (short*)p;  p += SZ_XPW;
    short* dtwb = (short*)p;  p += SZ_DTW;
    short* xinb = (short*)p;  p += SZ_BH;
    short* szb  = (short*)p;  p += SZ_BH;
    short* yb   = (short*)p;  p += 3 * SZ_BH;          // y, 3 dirs
    short* dtrb = (short*)p;  p += 3 * SZ_DTR;         // dtr, 3 dirs
    short* xcbb = (short*)p;  p += (size_t)ndir * SZ_BH;
    float* bc   = p;          p += (size_t)ndir * SZ_BC;
    short* Fg   = (short*)p;  p += (size_t)ndir * SZ_F;    // Hin in-place (bf16)
    float* SDg  = p;          p += (size_t)ndir * SD_DIR;

    k_cvt<<<dim3(480), dim3(256), 0, stream>>>(
        in_proj, out_proj, xpw[0], xpw[1], xpw[2], dtw[0], dtw[1], dtw[2],
        Wib, Wob, xpwb, dtwb);
    k_ln_t<<<dim3(B_SZ * 64), dim3(256), 0, stream>>>(x, ln_w, ln_b, xnb);
    k_inproj_mfma<<<dim3(512), dim3(256), 0, stream>>>(xnb, Wib, xinb, szb);

    for (int d0 = 0; d0 < 3; d0 += ndir) {
        k_conv3<<<dim3(512 * ndir), dim3(256), 0, stream>>>(
            xinb, conv_w[0], conv_w[1], conv_w[2],
            conv_b[0], conv_b[1], conv_b[2], xcbb, d0, xcb_str);
        k_proj3_mfma<<<dim3(512 * ndir), dim3(256), 0, stream>>>(
            xcbb, xpwb, dtrb, bc, d0, xcb_str, bc_str);
        k_scan1<<<dim3(512 * ndir), dim3(256), 0, stream>>>(
            dtrb, xcbb, bc, dtwb, dtb[0], dtb[1], dtb[2],
            A_log[0], A_log[1], A_log[2], Fg, SDg,
            d0, xcb_str, bc_str);
        k_comb<<<dim3(64 * ndir), dim3(256), 0, stream>>>(
            Fg, SDg, A_log[0], A_log[1], A_log[2], d0);
        k_scan2<<<dim3(512 * ndir), dim3(256), 0, stream>>>(
            dtrb, xcbb, bc, dtwb, dtb[0], dtb[1], dtb[2],
            A_log[0], A_log[1], A_log[2],
            Dp[0], Dp[1], Dp[2], Fg, yb, d0, xcb_str, bc_str);
    }

    k_out3_mfma<<<dim3(256), dim3(256), 0, stream>>>(
        yb, szb, Wob, x, out);
}

// Round 15
// 232.838 us; speedup vs baseline: 1.1668x; 1.1668x over previous
//
#include <hip/hip_runtime.h>
#include <hip/hip_bf16.h>
#include <cstdint>

#define B_SZ 2
#define DIM 256
#define L_SEQ 4096
#define D_INNER 512
#define DT_RANK 16
#define D_STATE 16
#define NCHUNK 128
#define CHUNK 32

static constexpr size_t SZ_BIG_SH = (size_t)B_SZ * L_SEQ * D_INNER;  // 4M shorts
static constexpr size_t F_DIR  = (size_t)B_SZ * NCHUNK * D_STATE * D_INNER; // 2M elems/dir
static constexpr size_t SD_DIR = (size_t)B_SZ * NCHUNK * D_INNER;           // 128K floats/dir

typedef __attribute__((ext_vector_type(8))) short short8v;
typedef __attribute__((ext_vector_type(4))) short short4v;
typedef __attribute__((ext_vector_type(4))) float f32x4;

__device__ __forceinline__ float silu_f(float v) {
    return v / (1.0f + __expf(-v));
}
__device__ __forceinline__ float softplus_fast(float v) {
    return (v > 15.0f) ? v : __logf(1.0f + __expf(v));
}
__device__ __forceinline__ short f2bf(float f) {   // RNE fp32 -> bf16 bits
    uint32_t u = __float_as_uint(f);
    u += 0x7fffu + ((u >> 16) & 1u);
    return (short)(u >> 16);
}
__device__ __forceinline__ float bf2f(short s) {
    return __uint_as_float(((uint32_t)(uint16_t)s) << 16);
}
// direction map: sequence position p -> original flat index l (involutions)
__device__ __forceinline__ int dir_map(int p, int dm) {
    if (dm == 0) return p;
    if (dm == 1) return (L_SEQ - 1) - p;
    return ((p & 63) << 6) | (p >> 6);   // 64x64 transpose
}
// dA[s] = r1^(s+1) via binary power tree (A_log = log(1..16) structure)
__device__ __forceinline__ void pow_dA(float r1, float* dA) {
    const float r2 = r1 * r1, r4 = r2 * r2, r8 = r4 * r4;
    dA[0] = r1;         dA[1] = r2;         dA[2] = r2 * r1;    dA[3] = r4;
    dA[4] = r4 * r1;    dA[5] = r4 * r2;    dA[6] = r4 * dA[2]; dA[7] = r8;
    dA[8] = r8 * r1;    dA[9] = r8 * r2;    dA[10] = r8 * dA[2]; dA[11] = r8 * r4;
    dA[12] = r8 * dA[4]; dA[13] = r8 * dA[5]; dA[14] = r8 * dA[6]; dA[15] = r8 * r8;
}

// ---------------------------------------------------------------------------
// Kernel 0: convert weights to bf16.
// ---------------------------------------------------------------------------
__global__ __launch_bounds__(256) void k_cvt(
    const float* __restrict__ Wi, const float* __restrict__ Wo,
    const float* __restrict__ xp0, const float* __restrict__ xp1, const float* __restrict__ xp2,
    const float* __restrict__ dw0, const float* __restrict__ dw1, const float* __restrict__ dw2,
    short* __restrict__ Wib, short* __restrict__ Wob,
    short* __restrict__ xpwb, short* __restrict__ dtwb)
{
    const int idx = blockIdx.x * 256 + threadIdx.x;   // float4 chunk id
    const float* src; short* dst; int off;
    if (idx < 65536)        { src = Wi; dst = Wib; off = idx; }
    else if (idx < 98304)   { src = Wo; dst = Wob; off = idx - 65536; }
    else if (idx < 116736)  {
        int k = idx - 98304; const int d = k / 6144; k -= d * 6144;
        src = d == 0 ? xp0 : (d == 1 ? xp1 : xp2);
        dst = xpwb + (size_t)d * 24576; off = k;
    } else {
        int k = idx - 116736; const int d = k / 2048; k -= d * 2048;
        src = d == 0 ? dw0 : (d == 1 ? dw1 : dw2);
        dst = dtwb + (size_t)d * 8192; off = k;
    }
    const float4 v = *(const float4*)(src + (size_t)off * 4);
    short4v p = {f2bf(v.x), f2bf(v.y), f2bf(v.z), f2bf(v.w)};
    *(short4v*)(dst + (size_t)off * 4) = p;
}

// ---------------------------------------------------------------------------
// Kernel 1a: LayerNorm via LDS transpose tile; writes xn as bf16.
// ---------------------------------------------------------------------------
__global__ __launch_bounds__(256) void k_ln_t(
    const float* __restrict__ x, const float* __restrict__ lnw,
    const float* __restrict__ lnb, short* __restrict__ xnb)
{
    __shared__ float xt[64][257];
    __shared__ float red[2][4][64];
    __shared__ float muS[64], rsS[64];
    __shared__ float lnwS[DIM], lnbS[DIM];

    const int b  = blockIdx.x >> 6;
    const int l0 = (blockIdx.x & 63) << 6;
    const int t  = threadIdx.x;
    lnwS[t] = lnw[t]; lnbS[t] = lnb[t];

    const float* xb = x + (size_t)b * DIM * L_SEQ + l0;
#pragma unroll
    for (int it = 0; it < 16; ++it) {
        const int idx = it * 256 + t;
        const int c = idx >> 4, pos = (idx & 15) << 2;
        const float4 v = *(const float4*)(xb + (size_t)c * L_SEQ + pos);
        xt[pos + 0][c] = v.x; xt[pos + 1][c] = v.y;
        xt[pos + 2][c] = v.z; xt[pos + 3][c] = v.w;
    }
    __syncthreads();
    {
        const int l = t & 63, cq = t >> 6;
        float sum = 0.f, sq = 0.f;
        for (int c = cq * 64; c < cq * 64 + 64; ++c) {
            const float v = xt[l][c];
            sum += v; sq += v * v;
        }
        red[0][cq][l] = sum; red[1][cq][l] = sq;
    }
    __syncthreads();
    if (t < 64) {
        const float s  = red[0][0][t] + red[0][1][t] + red[0][2][t] + red[0][3][t];
        const float q2 = red[1][0][t] + red[1][1][t] + red[1][2][t] + red[1][3][t];
        const float mu  = s * (1.0f / DIM);
        const float var = q2 * (1.0f / DIM) - mu * mu;
        muS[t] = mu; rsS[t] = rsqrtf(var + 1e-5f);
    }
    __syncthreads();
#pragma unroll
    for (int it = 0; it < 32; ++it) {
        const int idx = it * 256 + t;
        const int l = idx >> 7, cp = (idx & 127) << 1;
        const float mu = muS[l], rs = rsS[l];
        short2 p;
        p.x = f2bf((xt[l][cp + 0] - mu) * rs * lnwS[cp + 0] + lnbS[cp + 0]);
        p.y = f2bf((xt[l][cp + 1] - mu) * rs * lnwS[cp + 1] + lnbS[cp + 1]);
        *(short2*)(xnb + (size_t)((b * L_SEQ) + l0 + l) * DIM + cp) = p;
    }
}

// ---------------------------------------------------------------------------
// Kernel 1b: in_proj via MFMA; outputs xin and sz as bf16.
// ---------------------------------------------------------------------------
__global__ __launch_bounds__(256) void k_inproj_mfma(
    const short* __restrict__ xnb, const short* __restrict__ Wib,
    short* __restrict__ xinb, short* __restrict__ szb)
{
    const int mblk = blockIdx.x >> 2;
    const int q    = blockIdx.x & 3;
    const int t = threadIdx.x;
    const int w = t >> 6, l = t & 63;
    const int m0 = mblk * 64 + w * 16;
    const int n0 = q * 256;
    const int lrow = l & 15, lk = l >> 4;

    short8v a[8];
    {
        const short* ap = xnb + (size_t)(m0 + lrow) * DIM + lk * 8;
#pragma unroll
        for (int kk = 0; kk < 8; ++kk)
            a[kk] = *(const short8v*)(ap + kk * 32);
    }

#pragma unroll 4
    for (int nf = 0; nf < 16; ++nf) {
        const int n = n0 + nf * 16 + lrow;
        const short* bp = Wib + (size_t)n * DIM + lk * 8;
        f32x4 acc = {0.f, 0.f, 0.f, 0.f};
#pragma unroll
        for (int kk = 0; kk < 8; ++kk)
            acc = __builtin_amdgcn_mfma_f32_16x16x32_bf16(
                a[kk], *(const short8v*)(bp + kk * 32), acc, 0, 0, 0);
        const int col = n;
        const int r0  = m0 + lk * 4;
        if (n0 < D_INNER) {
#pragma unroll
            for (int j = 0; j < 4; ++j)
                xinb[(size_t)(r0 + j) * D_INNER + col] = f2bf(acc[j]);
        } else {
#pragma unroll
            for (int j = 0; j < 4; ++j)
                szb[(size_t)(r0 + j) * D_INNER + (col - D_INNER)] = f2bf(silu_f(acc[j]));
        }
    }
}

// ---------------------------------------------------------------------------
// Kernel 2: causal conv (K=4) + SiLU; bf16 in/out, sliding-window regs.
// ---------------------------------------------------------------------------
__global__ __launch_bounds__(256) void k_conv3(
    const short* __restrict__ xinb,
    const float* __restrict__ cw0, const float* __restrict__ cw1, const float* __restrict__ cw2,
    const float* __restrict__ cb0, const float* __restrict__ cb1, const float* __restrict__ cb2,
    short* __restrict__ xcbb, int dir_base, size_t xcb_str)
{
    const int rel = blockIdx.x >> 9;
    const int rem = blockIdx.x & 511;
    const int dir = dir_base + rel;
    const int b   = rem >> 8;
    const int p0  = (rem & 255) << 4;
    const int t   = threadIdx.x;

    const float* cw = dir == 0 ? cw0 : (dir == 1 ? cw1 : cw2);
    const float* cb = dir == 0 ? cb0 : (dir == 1 ? cb1 : cb2);
    short* xcb = xcbb + (size_t)rel * xcb_str;

    __shared__ short s[19][D_INNER];   // 19.5 KB
    for (int i = 0; i < 19; ++i) {
        const int pk = p0 - 3 + i;
        short2 v = {0, 0};
        if (pk >= 0) {
            const int lo = dir_map(pk, dir);
            v = *(const short2*)(xinb + ((size_t)b * L_SEQ + lo) * D_INNER + t * 2);
        }
        *(short2*)&s[i][t * 2] = v;
    }
    __syncthreads();

#pragma unroll
    for (int half = 0; half < 2; ++half) {
        const int d = half * 256 + t;
        const float4 wv = *(const float4*)(cw + d * 4);
        const float bb = cb[d];
        float x0 = bf2f(s[0][d]), x1 = bf2f(s[1][d]), x2 = bf2f(s[2][d]);
#pragma unroll
        for (int i = 0; i < 16; ++i) {
            const float x3 = bf2f(s[i + 3][d]);
            const float a = bb + wv.x * x0 + wv.y * x1 + wv.z * x2 + wv.w * x3;
            xcb[((size_t)b * L_SEQ + p0 + i) * D_INNER + d] = f2bf(silu_f(a));
            x0 = x1; x1 = x2; x2 = x3;
        }
    }
}

// ---------------------------------------------------------------------------
// Kernel 3: x_proj + dt_proj via MFMA, K-split across 4 waves.
// ---------------------------------------------------------------------------
__global__ __launch_bounds__(256) void k_proj3_mfma(
    const short* __restrict__ xcbb, const short* __restrict__ xpwb,
    const short* __restrict__ dtwb,
    const float* __restrict__ dtb0, const float* __restrict__ dtb1, const float* __restrict__ dtb2,
    short* __restrict__ dtYb, float* __restrict__ bcbuf,
    int dir_base, size_t xcb_str, size_t bc_str)
{
    const int rel = blockIdx.x >> 9;         // 512 blocks per dir
    const int rem = blockIdx.x & 511;
    const int dir = dir_base + rel;
    const int m0  = rem * 16;
    const int t = threadIdx.x;
    const int w = t >> 6, l = t & 63;        // w = K-quarter
    const int lrow = l & 15, lk = l >> 4;

    const short* xcb = xcbb + (size_t)rel * xcb_str;
    const short* xpw = xpwb + (size_t)dir * (48 * 512);
    const short* dtw = dtwb + (size_t)dir * (512 * 16);
    const float* dtb = dir == 0 ? dtb0 : (dir == 1 ? dtb1 : dtb2);
    short* dt = dtYb + (size_t)dir * SZ_BIG_SH;
    float* bc = bcbuf + (size_t)rel * bc_str;

    __shared__ float red[4][3][16][17];   // padded row stride 17: no conflicts
    __shared__ short xdblb[16][16];       // dtr bf16
    __shared__ float dtbS[512];

    dtbS[t] = dtb[t]; dtbS[t + 256] = dtb[t + 256];

    short8v a[4];
    {
        const short* ap = xcb + (size_t)(m0 + lrow) * D_INNER + w * 128 + lk * 8;
#pragma unroll
        for (int kk = 0; kk < 4; ++kk)
            a[kk] = *(const short8v*)(ap + kk * 32);
    }

#pragma unroll
    for (int nf = 0; nf < 3; ++nf) {
        f32x4 acc = {0.f, 0.f, 0.f, 0.f};
        const short* bp = xpw + (size_t)(nf * 16 + lrow) * D_INNER + w * 128 + lk * 8;
#pragma unroll
        for (int kk = 0; kk < 4; ++kk)
            acc = __builtin_amdgcn_mfma_f32_16x16x32_bf16(
                a[kk], *(const short8v*)(bp + kk * 32), acc, 0, 0, 0);
#pragma unroll
        for (int j = 0; j < 4; ++j)
            red[w][nf][lk * 4 + j][lrow] = acc[j];
    }
    __syncthreads();

#pragma unroll
    for (int i = 0; i < 3; ++i) {
        const int nf = i;
        const int row = (t >> 4) & 15, col = t & 15;
        const float v = red[0][nf][row][col] + red[1][nf][row][col]
                      + red[2][nf][row][col] + red[3][nf][row][col];
        if (nf == 0) xdblb[row][col] = f2bf(v);
        else         bc[(size_t)(m0 + row) * 32 + (nf - 1) * 16 + col] = v;
    }
    __syncthreads();

    short8v adt = {0, 0, 0, 0, 0, 0, 0, 0};
    if (lk < 2) adt = *(const short8v*)&xdblb[lrow][lk * 8];

#pragma unroll
    for (int nbw = 0; nbw < 8; ++nbw) {
        const int nb = w * 8 + nbw;
        short8v bdt = {0, 0, 0, 0, 0, 0, 0, 0};
        if (lk < 2) bdt = *(const short8v*)(dtw + (size_t)(nb * 16 + lrow) * 16 + lk * 8);
        f32x4 acc = {0.f, 0.f, 0.f, 0.f};
        acc = __builtin_amdgcn_mfma_f32_16x16x32_bf16(adt, bdt, acc, 0, 0, 0);
        const int d = nb * 16 + lrow;
        const float bias = dtbS[d];
#pragma unroll
        for (int j = 0; j < 4; ++j)
            dt[(size_t)(m0 + lk * 4 + j) * D_INNER + d] = f2bf(softplus_fast(acc[j] + bias));
    }
}

// block-uniform fast-structure vote: A_log row ~ log(1..16)?
__device__ __forceinline__ bool fast_vote(const float* Al_d, int t, int* flagS) {
    bool ok = true;
    const float a0 = __expf(Al_d[0]);   // ~1
#pragma unroll
    for (int s = 1; s < 16; ++s) {
        const float v = __expf(Al_d[s]);
        const float e = (float)(s + 1) * a0;
        ok = ok && (fabsf(v - e) <= 1e-3f * e);
    }
    if (t == 0) *flagS = 1;
    __syncthreads();
    if (!ok) *flagS = 0;
    __syncthreads();
    return *flagS != 0;
}

// ---------------------------------------------------------------------------
// Scan bodies. dt read from memory (materialized). F/Hin stored bf16.
// P never stored: P = exp2(As2[s]*sumdt) (valid for any A).
// ---------------------------------------------------------------------------
template<bool FAST>
__device__ __forceinline__ void scan1_body(
    const short* dtp, const short* xcp, const float* bcp,
    short (*dts)[256], short (*xcs)[256], float (*bcs)[16],
    const float* Al_d, int t, short* F_o, float* SD_o)
{
    float As20, As2[16];
    if (FAST) {
        As20 = -__expf(Al_d[0]) * 1.44269504f;
    } else {
#pragma unroll
        for (int s = 0; s < 16; ++s) As2[s] = -__expf(Al_d[s]) * 1.44269504f;
        As20 = As2[0];
    }
    float h[16];
#pragma unroll
    for (int s = 0; s < 16; ++s) h[s] = 0.f;
    float sumdt = 0.f;

    for (int tile = 0; tile < CHUNK / 16; ++tile) {
        const int p0 = tile * 16;
#pragma unroll
        for (int rep = 0; rep < 2; ++rep) {
            const int idx = rep * 256 + t;
            const int jr = idx >> 5, c8 = (idx & 31) << 3;
            *(short8v*)&dts[jr][c8] = *(const short8v*)(dtp + (size_t)(p0 + jr) * D_INNER + c8);
            *(short8v*)&xcs[jr][c8] = *(const short8v*)(xcp + (size_t)(p0 + jr) * D_INNER + c8);
        }
        if (t < 64) {
            const int jr = t >> 2, c4 = (t & 3) << 2;
            *(float4*)&bcs[jr][c4] = *(const float4*)(bcp + (size_t)(p0 + jr) * 32 + c4);
        }
        __syncthreads();

#pragma unroll
        for (int j = 0; j < 16; ++j) {
            const float dtv = bf2f(dts[j][t]);
            const float xv  = bf2f(xcs[j][t]);
            sumdt += dtv;
            const float dtx = dtv * xv;
            float Bv[16];
#pragma unroll
            for (int s4 = 0; s4 < 4; ++s4) {
                const float4 bb = *(const float4*)&bcs[j][s4 * 4];
                Bv[s4 * 4 + 0] = bb.x; Bv[s4 * 4 + 1] = bb.y;
                Bv[s4 * 4 + 2] = bb.z; Bv[s4 * 4 + 3] = bb.w;
            }
            if (FAST) {
                float dA[16];
                pow_dA(exp2f(dtv * As20), dA);
#pragma unroll
                for (int s = 0; s < 16; ++s)
                    h[s] = fmaf(dA[s], h[s], dtx * Bv[s]);
            } else {
#pragma unroll
                for (int s = 0; s < 16; ++s)
                    h[s] = fmaf(exp2f(dtv * As2[s]), h[s], dtx * Bv[s]);
            }
        }
        __syncthreads();
    }
#pragma unroll
    for (int s = 0; s < 16; ++s)
        F_o[(size_t)s * D_INNER] = f2bf(h[s]);
    *SD_o = sumdt;
}

template<bool FAST>
__device__ __forceinline__ void scan2_body(
    short* dtp, const short* xcp, const float* bcp,
    short (*dts)[256], short (*xcs)[256], float (*bcs)[32],
    const float* Al_d, int t, float Dv, const short* Hin_o)
{
    float As20, As2[16];
    if (FAST) {
        As20 = -__expf(Al_d[0]) * 1.44269504f;
    } else {
#pragma unroll
        for (int s = 0; s < 16; ++s) As2[s] = -__expf(Al_d[s]) * 1.44269504f;
        As20 = As2[0];
    }
    float h[16];
#pragma unroll
    for (int s = 0; s < 16; ++s)
        h[s] = bf2f(Hin_o[(size_t)s * D_INNER]);

    for (int tile = 0; tile < CHUNK / 16; ++tile) {
        const int p0 = tile * 16;
#pragma unroll
        for (int rep = 0; rep < 2; ++rep) {
            const int idx = rep * 256 + t;
            const int jr = idx >> 5, c8 = (idx & 31) << 3;
            // last consumer of dt/xc: nontemporal loads keep L2 for Hin/bc
            *(short8v*)&dts[jr][c8] = __builtin_nontemporal_load(
                (const short8v*)(dtp + (size_t)(p0 + jr) * D_INNER + c8));
            *(short8v*)&xcs[jr][c8] = __builtin_nontemporal_load(
                (const short8v*)(xcp + (size_t)(p0 + jr) * D_INNER + c8));
        }
        if (t < 128) {
            const int jr = t >> 3, c4 = (t & 7) << 2;
            *(float4*)&bcs[jr][c4] = *(const float4*)(bcp + (size_t)(p0 + jr) * 32 + c4);
        }
        __syncthreads();

#pragma unroll
        for (int j = 0; j < 16; ++j) {
            const float dtv = bf2f(dts[j][t]);
            const float xv  = bf2f(xcs[j][t]);
            const float dtx = dtv * xv;
            float Bv[16], Cv[16];
#pragma unroll
            for (int s4 = 0; s4 < 4; ++s4) {
                const float4 bb = *(const float4*)&bcs[j][s4 * 4];
                const float4 cc = *(const float4*)&bcs[j][16 + s4 * 4];
                Bv[s4 * 4 + 0] = bb.x; Bv[s4 * 4 + 1] = bb.y;
                Bv[s4 * 4 + 2] = bb.z; Bv[s4 * 4 + 3] = bb.w;
                Cv[s4 * 4 + 0] = cc.x; Cv[s4 * 4 + 1] = cc.y;
                Cv[s4 * 4 + 2] = cc.z; Cv[s4 * 4 + 3] = cc.w;
            }
            float y = xv * Dv;
            if (FAST) {
                float dA[16];
                pow_dA(exp2f(dtv * As20), dA);
#pragma unroll
                for (int s = 0; s < 16; ++s) {
                    h[s] = fmaf(dA[s], h[s], dtx * Bv[s]);
                    y = fmaf(h[s], Cv[s], y);
                }
            } else {
#pragma unroll
                for (int s = 0; s < 16; ++s) {
                    h[s] = fmaf(exp2f(dtv * As2[s]), h[s], dtx * Bv[s]);
                    y = fmaf(h[s], Cv[s], y);
                }
            }
            // y overwrites consumed dt; no near-term consumer -> nontemporal
            __builtin_nontemporal_store(f2bf(y), dtp + (size_t)(p0 + j) * D_INNER + t);
        }
        __syncthreads();
    }
}

// ---------------------------------------------------------------------------
// Kernel 4a: per-chunk transition. Grid per dir = 2(b) x 128(chunk) x 2(half).
// ---------------------------------------------------------------------------
__global__ __launch_bounds__(256, 4) void k_scan1(
    const short* __restrict__ dtYb, const short* __restrict__ xcbb,
    const float* __restrict__ bcb,
    const float* __restrict__ Al0, const float* __restrict__ Al1, const float* __restrict__ Al2,
    short* __restrict__ Fg, float* __restrict__ SDg,
    int dir_base, size_t xcb_str, size_t bc_str)
{
    const int rel = blockIdx.x >> 9;         // 512 blocks per dir
    const int rem = blockIdx.x & 511;
    const int dir = dir_base + rel;
    const int b     = rem >> 8;
    const int chunk = (rem >> 1) & 127;
    const int half  = rem & 1;
    const int t = threadIdx.x;
    const int d = half * 256 + t;

    const short* dtg = dtYb + (size_t)dir * SZ_BIG_SH;
    const short* xcg = xcbb + (size_t)rel * xcb_str;
    const float* bcg = bcb + (size_t)rel * bc_str;
    const float* Al = dir == 0 ? Al0 : (dir == 1 ? Al1 : Al2);
    short* F  = Fg  + (size_t)rel * F_DIR;
    float* SD = SDg + (size_t)rel * SD_DIR;

    __shared__ short dts[16][256];   // 8 KB
    __shared__ short xcs[16][256];   // 8 KB
    __shared__ float bcs[16][16];    // 1 KB
    __shared__ int flagS;

    const size_t rowbase = (size_t)b * L_SEQ + chunk * CHUNK;
    const short* dtp = dtg + rowbase * D_INNER + half * 256;
    const short* xcp = xcg + rowbase * D_INNER + half * 256;
    const float* bcp = bcg + rowbase * 32;
    const float* Al_d = Al + d * D_STATE;
    const size_t fo  = ((size_t)b * NCHUNK + chunk) * (D_STATE * D_INNER) + d;
    const size_t sdo = ((size_t)b * NCHUNK + chunk) * D_INNER + d;

    const bool fast = fast_vote(Al_d, t, &flagS);
    if (fast) scan1_body<true >(dtp, xcp, bcp, dts, xcs, bcs, Al_d, t, F + fo, SD + sdo);
    else      scan1_body<false>(dtp, xcp, bcp, dts, xcs, bcs, Al_d, t, F + fo, SD + sdo);
}

// ---------------------------------------------------------------------------
// Kernel 4b: sequential combine; Hin (bf16) written IN PLACE over F.
// P recomputed from sumdt: P = exp2(As2 * sumdt).
// ---------------------------------------------------------------------------
__global__ __launch_bounds__(256) void k_comb(
    short* __restrict__ Fg, const float* __restrict__ SDg,
    const float* __restrict__ Al0, const float* __restrict__ Al1, const float* __restrict__ Al2,
    int dir_base)
{
    const int rel = blockIdx.x >> 6;         // 64 blocks per dir
    const int dir = dir_base + rel;
    const int gid = (blockIdx.x & 63) * 256 + threadIdx.x;   // 16384
    const int b   = gid >> 13;
    const int rem = gid & 8191;              // s*512 + d
    const int s   = rem >> 9;
    const int d   = rem & 511;

    const float* Al = dir == 0 ? Al0 : (dir == 1 ? Al1 : Al2);
    const float As2 = -__expf(Al[d * D_STATE + s]) * 1.44269504f;

    short* F        = Fg  + (size_t)rel * F_DIR;
    const float* SD = SDg + (size_t)rel * SD_DIR;

    float h = 0.f;
    for (int c = 0; c < NCHUNK; ++c) {
        const size_t base = (size_t)(b * NCHUNK + c);
        const size_t i  = (base << 13) + rem;
        const float sd  = SD[(base << 9) + d];
        const float P   = exp2f(As2 * sd);
        const float fv  = bf2f(F[i]);
        F[i] = f2bf(h);                      // Hin for chunk c
        h = fmaf(P, h, fv);
    }
}

// ---------------------------------------------------------------------------
// Kernel 4c: full scan; y bf16 in place over dt. Hin read from F (bf16).
// ---------------------------------------------------------------------------
__global__ __launch_bounds__(256, 4) void k_scan2(
    short* dtYb,                              // bf16 dt in, bf16 y out
    const short* __restrict__ xcbb, const float* __restrict__ bcb,
    const float* __restrict__ Al0, const float* __restrict__ Al1, const float* __restrict__ Al2,
    const float* __restrict__ Dp0, const float* __restrict__ Dp1, const float* __restrict__ Dp2,
    const short* __restrict__ Hing,
    int dir_base, size_t xcb_str, size_t bc_str)
{
    const int rel = blockIdx.x >> 9;
    const int rem = blockIdx.x & 511;
    const int dir = dir_base + rel;
    const int b     = rem >> 8;
    const int chunk = (rem >> 1) & 127;
    const int half  = rem & 1;
    const int t = threadIdx.x;
    const int d = half * 256 + t;

    short* dtg      = dtYb + (size_t)dir * SZ_BIG_SH;
    const short* xcg = xcbb + (size_t)rel * xcb_str;
    const float* bcg = bcb + (size_t)rel * bc_str;
    const float* Al  = dir == 0 ? Al0 : (dir == 1 ? Al1 : Al2);
    const float* Dpp = dir == 0 ? Dp0 : (dir == 1 ? Dp1 : Dp2);
    const short* Hin = Hing + (size_t)rel * F_DIR;

    __shared__ short dts[16][256];
    __shared__ short xcs[16][256];
    __shared__ float bcs[16][32];
    __shared__ int flagS;

    const size_t rowbase = (size_t)b * L_SEQ + chunk * CHUNK;
    short* dtp       = dtg + rowbase * D_INNER + half * 256;
    const short* xcp = xcg + rowbase * D_INNER + half * 256;
    const float* bcp = bcg + rowbase * 32;
    const float* Al_d = Al + d * D_STATE;
    const float Dv = Dpp[d];
    const size_t fo = ((size_t)b * NCHUNK + chunk) * (D_STATE * D_INNER) + d;

    const bool fast = fast_vote(Al_d, t, &flagS);
    if (fast) scan2_body<true >(dtp, xcp, bcp, dts, xcs, bcs, Al_d, t, Dv, Hin + fo);
    else      scan2_body<false>(dtp, xcp, bcp, dts, xcs, bcs, Al_d, t, Dv, Hin + fo);
}

// ---------------------------------------------------------------------------
// Kernel 5: out_proj via MFMA; y0/y1/y2/sz all bf16.
// ---------------------------------------------------------------------------
__global__ __launch_bounds__(256) void k_out3_mfma(
    const short* __restrict__ yall, const short* __restrict__ szb,
    const short* __restrict__ Wob, const float* __restrict__ x,
    float* __restrict__ out)
{
    __shared__ short ytb[32][512];           // 32 KB
    const int tile = blockIdx.x;
    const int b  = tile >> 7;
    const int l0 = (tile & 127) << 5;
    const int t  = threadIdx.x;

    const short* y0 = yall;
    const short* y1 = yall + SZ_BIG_SH;
    const short* y2 = yall + 2 * SZ_BIG_SH;
    const size_t rb = (size_t)b * L_SEQ;

#pragma unroll
    for (int it = 0; it < 8; ++it) {
        const int idx = it * 256 + t;        // 2048 chunks of 8
        const int r  = idx >> 6;
        const int c8 = idx & 63;
        const int lrow = l0 + r;
        const int p1 = (L_SEQ - 1) - lrow;
        const int p2 = ((lrow & 63) << 6) | (lrow >> 6);
        const short8v s0 = *(const short8v*)(y0 + (rb + lrow) * D_INNER + c8 * 8);
        const short8v s1 = *(const short8v*)(y1 + (rb + p1)   * D_INNER + c8 * 8);
        const short8v s2 = *(const short8v*)(y2 + (rb + p2)   * D_INNER + c8 * 8);
        const short8v sv = *(const short8v*)(szb + (rb + lrow) * D_INNER + c8 * 8);
        short8v pk;
#pragma unroll
        for (int i = 0; i < 8; ++i)
            pk[i] = f2bf((bf2f(s0[i]) + bf2f(s1[i]) + bf2f(s2[i])) * bf2f(sv[i]));
        *(short8v*)&ytb[r][(c8 ^ (r & 7)) * 8] = pk;
    }
    __syncthreads();

    const int w = t >> 6, l = t & 63;
    const int lrow = l & 15, lk = l >> 4;
    const int nf = w & 1;
    const int j0 = (w >> 1) * 128;
    const int brow = nf * 16 + lrow;

    f32x4 acc[8];
#pragma unroll
    for (int jf = 0; jf < 8; ++jf) acc[jf] = {0.f, 0.f, 0.f, 0.f};

#pragma unroll 4
    for (int kk = 0; kk < 16; ++kk) {
        const int c8 = kk * 4 + lk;
        const short8v bfrag = *(const short8v*)&ytb[brow][(c8 ^ (brow & 7)) * 8];
#pragma unroll
        for (int jf = 0; jf < 8; ++jf) {
            const short8v afrag = *(const short8v*)(
                Wob + (size_t)(j0 + jf * 16 + lrow) * D_INNER + kk * 32 + lk * 8);
            acc[jf] = __builtin_amdgcn_mfma_f32_16x16x32_bf16(afrag, bfrag, acc[jf], 0, 0, 0);
        }
    }

    const int lcol = l0 + nf * 16 + lrow;
#pragma unroll
    for (int jf = 0; jf < 8; ++jf) {
        const int jr0 = j0 + jf * 16 + lk * 4;
#pragma unroll
        for (int j = 0; j < 4; ++j) {
            const size_t o = ((size_t)b * DIM + jr0 + j) * L_SEQ + lcol;
            out[o] = x[o] + acc[jf][j];
        }
    }
}

// ---------------------------------------------------------------------------
extern "C" void kernel_launch(void* const* d_in, const int* in_sizes, int n_in,
                              void* d_out, int out_size, void* d_ws, size_t ws_size,
                              hipStream_t stream)
{
    const float* x       = (const float*)d_in[0];
    const float* ln_w    = (const float*)d_in[1];
    const float* ln_b    = (const float*)d_in[2];
    const float* in_proj = (const float*)d_in[3];
    const float* conv_w[3] = {(const float*)d_in[4],  (const float*)d_in[10], (const float*)d_in[16]};
    const float* conv_b[3] = {(const float*)d_in[5],  (const float*)d_in[11], (const float*)d_in[17]};
    const float* xpw[3]    = {(const float*)d_in[6],  (const float*)d_in[12], (const float*)d_in[18]};
    const float* dtw[3]    = {(const float*)d_in[7],  (const float*)d_in[13], (const float*)d_in[19]};
    const float* dtb[3]    = {(const float*)d_in[8],  (const float*)d_in[14], (const float*)d_in[20]};
    const float* Dp[3]     = {(const float*)d_in[9],  (const float*)d_in[15], (const float*)d_in[21]};
    const float* A_log[3]  = {(const float*)d_in[22], (const float*)d_in[23], (const float*)d_in[24]};
    const float* out_proj  = (const float*)d_in[25];
    float* out = (float*)d_out;
    (void)in_sizes; (void)n_in; (void)out_size;

    const size_t NROW   = (size_t)B_SZ * L_SEQ;                       // 8192
    // float-slot sizes
    const size_t SZ_XNB = NROW * DIM / 2;            // 1,048,576
    const size_t SZ_WIB = 262144 / 2;
    const size_t SZ_WOB = 131072 / 2;
    const size_t SZ_XPW = 3 * 24576 / 2;
    const size_t SZ_DTW = 3 * 8192 / 2;
    const size_t SZ_BH  = NROW * D_INNER / 2;        // bf16 big buf = 2,097,152
    const size_t SZ_BC  = NROW * 32;                 // 262,144
    const size_t SZ_F   = F_DIR / 2;                 // bf16 F per dir (float slots)

    const size_t need_merged =
        SZ_XNB + SZ_WIB + SZ_WOB + SZ_XPW + SZ_DTW +
        2 * SZ_BH + 3 * SZ_BH + 3 * SZ_BH + 3 * SZ_BC +
        3 * (SZ_F + SD_DIR);
    const bool merged = ws_size >= need_merged * sizeof(float);
    const int ndir = merged ? 3 : 1;
    const size_t xcb_str = merged ? (SZ_BH * 2) : 0;   // SHORT units
    const size_t bc_str  = merged ? SZ_BC : 0;

    float* ws   = (float*)d_ws;
    float* p    = ws;
    short* xnb  = (short*)p;  p += SZ_XNB;
    short* Wib  = (short*)p;  p += SZ_WIB;
    short* Wob  = (short*)p;  p += SZ_WOB;
    short* xpwb = (short*)p;  p += SZ_XPW;
    short* dtwb = (short*)p;  p += SZ_DTW;
    short* xinb = (short*)p;  p += SZ_BH;
    short* szb  = (short*)p;  p += SZ_BH;
    short* dtYb = (short*)p;  p += 3 * SZ_BH;          // y in-place, 3 dirs
    short* xcbb = (short*)p;  p += (size_t)ndir * SZ_BH;
    float* bc   = p;          p += (size_t)ndir * SZ_BC;
    short* Fg   = (short*)p;  p += (size_t)ndir * SZ_F;    // Hin in-place (bf16)
    float* SDg  = p;          p += (size_t)ndir * SD_DIR;

    k_cvt<<<dim3(480), dim3(256), 0, stream>>>(
        in_proj, out_proj, xpw[0], xpw[1], xpw[2], dtw[0], dtw[1], dtw[2],
        Wib, Wob, xpwb, dtwb);
    k_ln_t<<<dim3(B_SZ * 64), dim3(256), 0, stream>>>(x, ln_w, ln_b, xnb);
    k_inproj_mfma<<<dim3(512), dim3(256), 0, stream>>>(xnb, Wib, xinb, szb);

    for (int d0 = 0; d0 < 3; d0 += ndir) {
        k_conv3<<<dim3(512 * ndir), dim3(256), 0, stream>>>(
            xinb, conv_w[0], conv_w[1], conv_w[2],
            conv_b[0], conv_b[1], conv_b[2], xcbb, d0, xcb_str);
        k_proj3_mfma<<<dim3(512 * ndir), dim3(256), 0, stream>>>(
            xcbb, xpwb, dtwb, dtb[0], dtb[1], dtb[2],
            dtYb, bc, d0, xcb_str, bc_str);
        k_scan1<<<dim3(512 * ndir), dim3(256), 0, stream>>>(
            dtYb, xcbb, bc, A_log[0], A_log[1], A_log[2], Fg, SDg,
            d0, xcb_str, bc_str);
        k_comb<<<dim3(64 * ndir), dim3(256), 0, stream>>>(
            Fg, SDg, A_log[0], A_log[1], A_log[2], d0);
        k_scan2<<<dim3(512 * ndir), dim3(256), 0, stream>>>(
            dtYb, xcbb, bc, A_log[0], A_log[1], A_log[2],
            Dp[0], Dp[1], Dp[2], Fg, d0, xcb_str, bc_str);
    }

    k_out3_mfma<<<dim3(256), dim3(256), 0, stream>>>(
        dtYb, szb, Wob, x, out);
}